// Round 1
// baseline (474.375 us; speedup 1.0000x reference)
//
#include <hip/hip_runtime.h>

#define NB 32      // batches
#define MM 448
#define CC 384
#define SS 512
#define KNN 8

// workspace byte offsets
#define WS_IDX   0u
#define WS_H1    524288u                 // int idx[32][512][8] before this
#define WS_PMAX  (WS_H1 + 4194304u)      // float h1[32][512][64]
#define WS_Q     (WS_PMAX + 262144u)     // float pmax[32][16][128]
#define WS_Y     (WS_Q + 49152u)         // float q[32][384]
#define WS_G2    (WS_Y + 131072u)        // float y[32][1024]
#define WS_BASEP (WS_G2 + 131072u)       // float g2[32][1024]
// basep: float[32][2][384]  -> end = 5390336 bytes (~5.2 MB of ws)

// ---------------------------------------------------------------- K1: KNN + gc1
__global__ __launch_bounds__(256) void k_knn_gc1(
    const float* __restrict__ skel,
    const float* __restrict__ w1root, const float* __restrict__ w1rel,
    const float* __restrict__ b1,
    int* __restrict__ idx_ws, float* __restrict__ h1_ws)
{
  int b = blockIdx.x >> 1;
  int half = blockIdx.x & 1;
  __shared__ __align__(16) float sk[SS * 4];
  const float* sb = skel + b * SS * 3;
  for (int t = threadIdx.x; t < SS; t += 256) {
    sk[t*4+0] = sb[t*3+0];
    sk[t*4+1] = sb[t*3+1];
    sk[t*4+2] = sb[t*3+2];
    sk[t*4+3] = 0.f;
  }
  __syncthreads();
  int i = half * 256 + (int)threadIdx.x;
  float xi = sk[i*4], yi = sk[i*4+1], zi = sk[i*4+2];
  float bd[KNN]; int bj[KNN];
#pragma unroll
  for (int k = 0; k < KNN; k++) { bd[k] = 3e38f; bj[k] = 0; }
  {
    // match reference arithmetic exactly: (dx^2 + dy^2) + dz^2, no fma contraction,
    // strict < so boundary ties keep the lower index (lax.top_k tie order).
#pragma clang fp contract(off)
    for (int j = 0; j < SS; j++) {
      float px = sk[j*4], py = sk[j*4+1], pz = sk[j*4+2];
      float dx = xi - px, dy = yi - py, dz = zi - pz;
      float d2 = (dx*dx + dy*dy) + dz*dz;
      if (j == i) continue;
      if (d2 < bd[KNN-1]) {
        bd[KNN-1] = d2; bj[KNN-1] = j;
#pragma unroll
        for (int k = KNN-1; k > 0; k--) {
          if (bd[k] < bd[k-1]) {
            float td = bd[k]; bd[k] = bd[k-1]; bd[k-1] = td;
            int tj = bj[k]; bj[k] = bj[k-1]; bj[k-1] = tj;
          }
        }
      }
    }
  }
  float a0 = 0.f, a1 = 0.f, a2 = 0.f;
#pragma unroll
  for (int k = 0; k < KNN; k++) {
    int j = bj[k];
    a0 += sk[j*4]; a1 += sk[j*4+1]; a2 += sk[j*4+2];
    idx_ws[(b*SS + i)*KNN + k] = j;
  }
  float* hrow = h1_ws + (size_t)(b*SS + i) * 64;
  for (int c = 0; c < 64; c += 4) {
    float4 r0 = *(const float4*)(w1root + c);
    float4 r1 = *(const float4*)(w1root + 64 + c);
    float4 r2 = *(const float4*)(w1root + 128 + c);
    float4 l0 = *(const float4*)(w1rel + c);
    float4 l1 = *(const float4*)(w1rel + 64 + c);
    float4 l2 = *(const float4*)(w1rel + 128 + c);
    float4 bb = *(const float4*)(b1 + c);
    float4 h;
    h.x = bb.x + xi*r0.x + yi*r1.x + zi*r2.x + a0*l0.x + a1*l1.x + a2*l2.x;
    h.y = bb.y + xi*r0.y + yi*r1.y + zi*r2.y + a0*l0.y + a1*l1.y + a2*l2.y;
    h.z = bb.z + xi*r0.z + yi*r1.z + zi*r2.z + a0*l0.z + a1*l1.z + a2*l2.z;
    h.w = bb.w + xi*r0.w + yi*r1.w + zi*r2.w + a0*l0.w + a1*l1.w + a2*l2.w;
    h.x = fmaxf(h.x, 0.f); h.y = fmaxf(h.y, 0.f);
    h.z = fmaxf(h.z, 0.f); h.w = fmaxf(h.w, 0.f);
    *(float4*)(hrow + c) = h;
  }
}

// ---------------------------------------------------------- K2: gc2 + chunk max
__global__ __launch_bounds__(256) void k_gc2_max(
    const float* __restrict__ h1_ws, const int* __restrict__ idx_ws,
    const float* __restrict__ w2root, const float* __restrict__ w2rel,
    const float* __restrict__ b2, float* __restrict__ pmax)
{
  int b = blockIdx.x, chunk = blockIdx.y;
  int i0 = chunk * 32;
  __shared__ float hr[32 * 65];   // +1 pad: avoid 8-way bank conflict on hr[r][k]
  __shared__ float ag[32 * 65];
  __shared__ int   nb[32 * 8];
  __shared__ float h2s[32 * 129];
  const float* h1b = h1_ws + (size_t)b * SS * 64;
  for (int t = threadIdx.x; t < 2048; t += 256)
    hr[(t >> 6)*65 + (t & 63)] = h1b[i0*64 + t];
  if (threadIdx.x < 256)
    nb[threadIdx.x] = idx_ws[(b*SS + i0)*KNN + threadIdx.x];
  __syncthreads();
  for (int t = threadIdx.x; t < 2048; t += 256) {
    int r = t >> 6, c = t & 63;
    float s = 0.f;
#pragma unroll
    for (int k = 0; k < KNN; k++) s += h1b[nb[r*8 + k]*64 + c];
    ag[r*65 + c] = s;
  }
  __syncthreads();
  {
    int r = threadIdx.x >> 3;
    int c0 = (threadIdx.x & 7) * 16;
    float acc[16];
#pragma unroll
    for (int u = 0; u < 16; u++) acc[u] = b2[c0 + u];
    for (int k = 0; k < 64; k++) {
      float hk = hr[r*65 + k], ak = ag[r*65 + k];
      const float4* wr = (const float4*)(w2root + k*128 + c0);
      const float4* wl = (const float4*)(w2rel  + k*128 + c0);
#pragma unroll
      for (int u = 0; u < 4; u++) {
        float4 w4 = wr[u], l4 = wl[u];
        acc[u*4+0] += hk*w4.x + ak*l4.x;
        acc[u*4+1] += hk*w4.y + ak*l4.y;
        acc[u*4+2] += hk*w4.z + ak*l4.z;
        acc[u*4+3] += hk*w4.w + ak*l4.w;
      }
    }
#pragma unroll
    for (int u = 0; u < 16; u++) h2s[r*129 + c0 + u] = acc[u];
  }
  __syncthreads();
  if (threadIdx.x < 128) {
    int c = threadIdx.x;
    float m = -3e38f;
#pragma unroll 8
    for (int r = 0; r < 32; r++) m = fmaxf(m, h2s[r*129 + c]);
    pmax[(b*16 + chunk)*128 + c] = m;
  }
}

// ------------------------------------------- K3: proxy -> kv -> v -> q (per batch)
__global__ __launch_bounds__(384) void k_chain1(
    const float* __restrict__ pmax,
    const float* __restrict__ proj_w, const float* __restrict__ proj_b,
    const float* __restrict__ attn_in_w, const float* __restrict__ attn_in_b,
    const float* __restrict__ attn_out_w, const float* __restrict__ attn_out_b,
    float* __restrict__ q_ws)
{
  int b = blockIdx.x, t = threadIdx.x;
  __shared__ __align__(16) float proxy[128];
  __shared__ __align__(16) float kv[CC];
  __shared__ __align__(16) float vv[CC];
  if (t < 128) {
    float m = -3e38f;
    for (int ch = 0; ch < 16; ch++) m = fmaxf(m, pmax[(b*16 + ch)*128 + t]);
    proxy[t] = m;
  }
  __syncthreads();
  {
    float acc = proj_b[t];
    for (int s = 0; s < 128; s++) acc += proxy[s] * proj_w[s*CC + t];
    kv[t] = acc;
  }
  __syncthreads();
  {
    const float* w = attn_in_w + (size_t)(2*CC + t) * CC;  // wv row
    float acc = attn_in_b[2*CC + t];
    for (int c = 0; c < CC; c += 4) {
      float4 x4 = *(const float4*)(kv + c);
      float4 w4 = *(const float4*)(w + c);
      acc += x4.x*w4.x + x4.y*w4.y + x4.z*w4.z + x4.w*w4.w;
    }
    vv[t] = acc;
  }
  __syncthreads();
  {
    const float* w = attn_out_w + (size_t)t * CC;
    float acc = attn_out_b[t];
    for (int c = 0; c < CC; c += 4) {
      float4 x4 = *(const float4*)(vv + c);
      float4 w4 = *(const float4*)(w + c);
      acc += x4.x*w4.x + x4.y*w4.y + x4.z*w4.z + x4.w*w4.w;
    }
    q_ws[b*CC + t] = acc;
  }
}

// ------------------------------------------------------- K4: inc1 + BN + leaky
__global__ __launch_bounds__(256) void k_inc1_bn(
    const float* __restrict__ q_ws, const float* __restrict__ inc1_w,
    const float* __restrict__ inc1_b,
    const float* __restrict__ bng, const float* __restrict__ bnb,
    const float* __restrict__ bnm, const float* __restrict__ bnv,
    float* __restrict__ y_ws)
{
  int b = blockIdx.x;
  int o = blockIdx.y * 256 + threadIdx.x;
  __shared__ __align__(16) float x[CC];
  for (int t = threadIdx.x; t < CC; t += 256) x[t] = q_ws[b*CC + t];
  __syncthreads();
  const float* w = inc1_w + (size_t)o * CC;
  float acc = inc1_b[o];
  for (int c = 0; c < CC; c += 4) {
    float4 x4 = *(const float4*)(x + c);
    float4 w4 = *(const float4*)(w + c);
    acc += x4.x*w4.x + x4.y*w4.y + x4.z*w4.z + x4.w*w4.w;
  }
  float z = bng[o] * (acc - bnm[o]) * rsqrtf(bnv[o] + 1e-5f) + bnb[o];
  y_ws[b*1024 + o] = (z >= 0.f) ? z : 0.2f * z;
}

// ------------------------------------------------------------------- K5: inc2
__global__ __launch_bounds__(256) void k_inc2(
    const float* __restrict__ y_ws, const float* __restrict__ inc2_w,
    const float* __restrict__ inc2_b, float* __restrict__ g2_ws)
{
  int b = blockIdx.x;
  int o = blockIdx.y * 256 + threadIdx.x;
  __shared__ __align__(16) float x[1024];
  for (int t = threadIdx.x; t < 1024; t += 256) x[t] = y_ws[b*1024 + t];
  __syncthreads();
  const float* w = inc2_w + (size_t)o * 1024;
  float acc = inc2_b[o];
  for (int c = 0; c < 1024; c += 4) {
    float4 x4 = *(const float4*)(x + c);
    float4 w4 = *(const float4*)(w + c);
    acc += x4.x*w4.x + x4.y*w4.y + x4.z*w4.z + x4.w*w4.w;
  }
  g2_ws[b*1024 + o] = acc;
}

// --------------------------------------- K6: base partials over c-halves of red_w
__global__ __launch_bounds__(384) void k_base(
    const float* __restrict__ g2_ws, const float* __restrict__ q_ws,
    const float* __restrict__ red_w, float* __restrict__ basep)
{
  int b = blockIdx.x, h = blockIdx.y;
  int o = threadIdx.x;                  // 384 threads = one output each
  __shared__ __align__(16) float x[704];
  int c0 = h * 704;
  for (int t = threadIdx.x; t < 704; t += 384) {
    int c = c0 + t;
    x[t] = (c < 1024) ? g2_ws[b*1024 + c] : q_ws[b*CC + (c - 1024)];
  }
  __syncthreads();
  float acc = 0.f;
  for (int cc = 0; cc < 704; cc += 4) {
    float4 x4 = *(const float4*)(x + cc);
    acc += x4.x * red_w[(size_t)(c0 + cc    )*CC + o];
    acc += x4.y * red_w[(size_t)(c0 + cc + 1)*CC + o];
    acc += x4.z * red_w[(size_t)(c0 + cc + 2)*CC + o];
    acc += x4.w * red_w[(size_t)(c0 + cc + 3)*CC + o];
  }
  basep[(b*2 + h)*CC + o] = acc;
}

// --------------------------------------------- K7: out = base + coarse @ red_w3
__global__ __launch_bounds__(256) void k_out(
    const float* __restrict__ basep, const float* __restrict__ red_b,
    const float* __restrict__ red_w, const float* __restrict__ coarse,
    float* __restrict__ out)
{
  int gid = blockIdx.x * 256 + threadIdx.x;   // < 32*448*96 exactly
  int c4 = gid % 96;
  int row = gid / 96;                          // b*448 + m
  int b = row / 448;
  int c = c4 * 4;
  float4 p0 = *(const float4*)(basep + (b*2 + 0)*CC + c);
  float4 p1 = *(const float4*)(basep + (b*2 + 1)*CC + c);
  float4 rb = *(const float4*)(red_b + c);
  const float* cr = coarse + (size_t)row * 3;
  float cx = cr[0], cy = cr[1], cz = cr[2];
  float4 w0 = *(const float4*)(red_w + (size_t)1408*CC + c);
  float4 w1 = *(const float4*)(red_w + (size_t)1409*CC + c);
  float4 w2 = *(const float4*)(red_w + (size_t)1410*CC + c);
  float4 o4;
  o4.x = p0.x + p1.x + rb.x + cx*w0.x + cy*w1.x + cz*w2.x;
  o4.y = p0.y + p1.y + rb.y + cx*w0.y + cy*w1.y + cz*w2.y;
  o4.z = p0.z + p1.z + rb.z + cx*w0.z + cy*w1.z + cz*w2.z;
  o4.w = p0.w + p1.w + rb.w + cx*w0.w + cy*w1.w + cz*w2.w;
  *(float4*)(out + (size_t)row*CC + c) = o4;
}

extern "C" void kernel_launch(void* const* d_in, const int* in_sizes, int n_in,
                              void* d_out, int out_size, void* d_ws, size_t ws_size,
                              hipStream_t stream)
{
  (void)in_sizes; (void)n_in; (void)out_size; (void)ws_size;
  // d_in[0] is q (B,M,C): provably unused — attention softmax is uniform.
  const float* coarse = (const float*)d_in[1];
  const float* skel   = (const float*)d_in[2];
  const float* g1wr   = (const float*)d_in[3];
  const float* g1wl   = (const float*)d_in[4];
  const float* g1b    = (const float*)d_in[5];
  const float* g2wr   = (const float*)d_in[6];
  const float* g2wl   = (const float*)d_in[7];
  const float* g2b    = (const float*)d_in[8];
  const float* projw  = (const float*)d_in[9];
  const float* projb  = (const float*)d_in[10];
  const float* aiw    = (const float*)d_in[11];
  const float* aib    = (const float*)d_in[12];
  const float* aow    = (const float*)d_in[13];
  const float* aob    = (const float*)d_in[14];
  const float* i1w    = (const float*)d_in[15];
  const float* i1b    = (const float*)d_in[16];
  const float* bng    = (const float*)d_in[17];
  const float* bnb    = (const float*)d_in[18];
  const float* bnm    = (const float*)d_in[19];
  const float* bnv    = (const float*)d_in[20];
  const float* i2w    = (const float*)d_in[21];
  const float* i2b    = (const float*)d_in[22];
  const float* redw   = (const float*)d_in[23];
  const float* redb   = (const float*)d_in[24];
  float* out = (float*)d_out;

  char* ws = (char*)d_ws;
  int*   idx_ws = (int*)(ws + WS_IDX);
  float* h1_ws  = (float*)(ws + WS_H1);
  float* pmax   = (float*)(ws + WS_PMAX);
  float* q_ws   = (float*)(ws + WS_Q);
  float* y_ws   = (float*)(ws + WS_Y);
  float* g2_ws  = (float*)(ws + WS_G2);
  float* basep  = (float*)(ws + WS_BASEP);

  k_knn_gc1<<<64, 256, 0, stream>>>(skel, g1wr, g1wl, g1b, idx_ws, h1_ws);
  k_gc2_max<<<dim3(32, 16), 256, 0, stream>>>(h1_ws, idx_ws, g2wr, g2wl, g2b, pmax);
  k_chain1<<<32, 384, 0, stream>>>(pmax, projw, projb, aiw, aib, aow, aob, q_ws);
  k_inc1_bn<<<dim3(32, 4), 256, 0, stream>>>(q_ws, i1w, i1b, bng, bnb, bnm, bnv, y_ws);
  k_inc2<<<dim3(32, 4), 256, 0, stream>>>(y_ws, i2w, i2b, g2_ws);
  k_base<<<dim3(32, 2), 384, 0, stream>>>(g2_ws, q_ws, redw, basep);
  k_out<<<5376, 256, 0, stream>>>(basep, redb, redw, coarse, out);
}

// Round 2
// 311.597 us; speedup vs baseline: 1.5224x; 1.5224x over previous
//
#include <hip/hip_runtime.h>

#define NB 32      // batches
#define MM 448
#define CC 384
#define SS 512
#define KNN 8

// workspace byte offsets
#define WS_IDX   0u
#define WS_H1    524288u                 // int idx[32][512][8] before this
#define WS_PMAX  (WS_H1 + 4194304u)      // float h1[32][512][64]
#define WS_Q     (WS_PMAX + 262144u)     // float pmax[32][16][128]
#define WS_Y     (WS_Q + 49152u)         // float y[32][1024]
#define WS_G2    (WS_Y + 131072u)        // float g2[32][1024]
#define WS_BASEP (WS_G2 + 131072u)       // float basep after g2
// kv/vv reuse the idx region (idx dead after K2; proxy-chain runs after K2)
#define WS_KV    WS_IDX
#define WS_VV    (WS_IDX + 49152u)

__device__ __forceinline__ float wave_sum(float v) {
#pragma unroll
  for (int m = 1; m < 64; m <<= 1) v += __shfl_xor(v, m, 64);
  return v;
}

// ------------------------------------------------- K1: KNN + gc1, wave-per-point
__global__ __launch_bounds__(256) void k_knn_gc1(
    const float* __restrict__ skel,
    const float* __restrict__ w1root, const float* __restrict__ w1rel,
    const float* __restrict__ b1,
    int* __restrict__ idx_ws, float* __restrict__ h1_ws)
{
  int b   = blockIdx.x >> 7;          // 128 groups of 4 points per batch
  int grp = blockIdx.x & 127;
  __shared__ __align__(16) float4 sk[SS];
  const float* sb = skel + b * SS * 3;
  for (int t = threadIdx.x; t < SS; t += 256)
    sk[t] = make_float4(sb[t*3+0], sb[t*3+1], sb[t*3+2], 0.f);
  __syncthreads();

  int wave = threadIdx.x >> 6, lane = threadIdx.x & 63;
  int i = grp * 4 + wave;             // this wave's point
  float4 pi = sk[i];

  // lane owns candidates j = lane + 64*t
  float bd[KNN];
#pragma unroll
  for (int t = 0; t < KNN; t++) {
    int j = lane + (t << 6);
    float4 p = sk[j];
    float d2;
    {
      // match reference arithmetic exactly: (dx^2+dy^2)+dz^2, no fma contraction
#pragma clang fp contract(off)
      float dx = pi.x - p.x, dy = pi.y - p.y, dz = pi.z - p.z;
      d2 = (dx*dx + dy*dy) + dz*dz;
    }
    bd[t] = (j == i) ? 3e38f : d2;
  }

  // 8 rounds: global argmin (tie -> lower j, matching lax.top_k stability)
  int win[KNN];
  int* idx_base = idx_ws + (size_t)(b*SS + i) * KNN;
#pragma unroll
  for (int t = 0; t < KNN; t++) {
    float bestd = bd[0]; int bests = 0;
#pragma unroll
    for (int s = 1; s < KNN; s++)
      if (bd[s] < bestd) { bestd = bd[s]; bests = s; }
    int bestj = lane + (bests << 6);
#pragma unroll
    for (int m = 1; m < 64; m <<= 1) {
      float od = __shfl_xor(bestd, m, 64);
      int   oj = __shfl_xor(bestj, m, 64);
      if (od < bestd || (od == bestd && oj < bestj)) { bestd = od; bestj = oj; }
    }
    win[t] = bestj;                               // uniform across wave
    if (lane == t) idx_base[t] = bestj;
    if ((bestj & 63) == lane) {
      int sl = bestj >> 6;
#pragma unroll
      for (int s = 0; s < KNN; s++) if (s == sl) bd[s] = 3e38f;
    }
  }

  // neighbor coordinate sum in k-order (matches reference sum order)
  float a0 = 0.f, a1 = 0.f, a2 = 0.f;
#pragma unroll
  for (int t = 0; t < KNN; t++) {
    float4 n = sk[win[t]];
    a0 += n.x; a1 += n.y; a2 += n.z;
  }

  // gc1: 64 channels = 64 lanes, coalesced
  int c = lane;
  float h = b1[c] + pi.x*w1root[c] + pi.y*w1root[64+c] + pi.z*w1root[128+c]
                  + a0*w1rel[c]   + a1*w1rel[64+c]   + a2*w1rel[128+c];
  h = fmaxf(h, 0.f);
  h1_ws[(size_t)(b*SS + i) * 64 + lane] = h;
}

// ---------------------------------------------------------- K2: gc2 + chunk max
__global__ __launch_bounds__(256) void k_gc2_max(
    const float* __restrict__ h1_ws, const int* __restrict__ idx_ws,
    const float* __restrict__ w2root, const float* __restrict__ w2rel,
    const float* __restrict__ b2, float* __restrict__ pmax)
{
  int b = blockIdx.x, chunk = blockIdx.y;
  int i0 = chunk * 32;
  __shared__ float hr[32 * 65];
  __shared__ float ag[32 * 65];
  __shared__ int   nb[32 * 8];
  __shared__ float h2s[32 * 129];
  const float* h1b = h1_ws + (size_t)b * SS * 64;
  for (int t = threadIdx.x; t < 2048; t += 256)
    hr[(t >> 6)*65 + (t & 63)] = h1b[i0*64 + t];
  if (threadIdx.x < 256)
    nb[threadIdx.x] = idx_ws[(b*SS + i0)*KNN + threadIdx.x];
  __syncthreads();
  for (int t = threadIdx.x; t < 2048; t += 256) {
    int r = t >> 6, c = t & 63;
    float s = 0.f;
#pragma unroll
    for (int k = 0; k < KNN; k++) s += h1b[nb[r*8 + k]*64 + c];
    ag[r*65 + c] = s;
  }
  __syncthreads();
  {
    int r = threadIdx.x >> 3;
    int c0 = (threadIdx.x & 7) * 16;
    float acc[16];
#pragma unroll
    for (int u = 0; u < 16; u++) acc[u] = b2[c0 + u];
    for (int k = 0; k < 64; k++) {
      float hk = hr[r*65 + k], ak = ag[r*65 + k];
      const float4* wr = (const float4*)(w2root + k*128 + c0);
      const float4* wl = (const float4*)(w2rel  + k*128 + c0);
#pragma unroll
      for (int u = 0; u < 4; u++) {
        float4 w4 = wr[u], l4 = wl[u];
        acc[u*4+0] += hk*w4.x + ak*l4.x;
        acc[u*4+1] += hk*w4.y + ak*l4.y;
        acc[u*4+2] += hk*w4.z + ak*l4.z;
        acc[u*4+3] += hk*w4.w + ak*l4.w;
      }
    }
#pragma unroll
    for (int u = 0; u < 16; u++) h2s[r*129 + c0 + u] = acc[u];
  }
  __syncthreads();
  if (threadIdx.x < 128) {
    int c = threadIdx.x;
    float m = -3e38f;
#pragma unroll 8
    for (int r = 0; r < 32; r++) m = fmaxf(m, h2s[r*129 + c]);
    pmax[(b*16 + chunk)*128 + c] = m;
  }
}

// ------------------------------------------------- K3a: proxy max + kv (coalesced)
__global__ __launch_bounds__(384) void k_proxy_kv(
    const float* __restrict__ pmax,
    const float* __restrict__ proj_w, const float* __restrict__ proj_b,
    float* __restrict__ kv_ws)
{
  int b = blockIdx.x, t = threadIdx.x;
  __shared__ float proxy[128];
  if (t < 128) {
    float m = -3e38f;
    for (int ch = 0; ch < 16; ch++) m = fmaxf(m, pmax[(b*16 + ch)*128 + t]);
    proxy[t] = m;
  }
  __syncthreads();
  float acc = proj_b[t];
  for (int s = 0; s < 128; s++) acc += proxy[s] * proj_w[s*CC + t];   // coalesced
  kv_ws[b*CC + t] = acc;
}

// ------------------------- K3b/K3c: generic 384->384 matvec, wave-per-output dot
__global__ __launch_bounds__(256) void k_mv384(
    const float* __restrict__ xin, const float* __restrict__ w, int row0,
    const float* __restrict__ bias, int bias0, float* __restrict__ out)
{
  int b = blockIdx.x, og = blockIdx.y;
  int wv = threadIdx.x >> 6, lane = threadIdx.x & 63;
  __shared__ float xs[CC];
  for (int t = threadIdx.x; t < CC; t += 256) xs[t] = xin[b*CC + t];
  __syncthreads();
  float x0 = xs[lane*6+0], x1 = xs[lane*6+1], x2 = xs[lane*6+2];
  float x3 = xs[lane*6+3], x4 = xs[lane*6+4], x5 = xs[lane*6+5];
#pragma unroll
  for (int u = 0; u < 8; u++) {
    int o = og*32 + wv*8 + u;
    const float* wr = w + (size_t)(row0 + o) * CC + lane*6;
    float2 wa = *(const float2*)wr;
    float2 wb = *(const float2*)(wr + 2);
    float2 wc = *(const float2*)(wr + 4);
    float p = wa.x*x0 + wa.y*x1 + wb.x*x2 + wb.y*x3 + wc.x*x4 + wc.y*x5;
    p = wave_sum(p);
    if (lane == 0) out[b*CC + o] = bias[bias0 + o] + p;
  }
}

// ------------------------------- K4: inc1 + BN + leaky, wave-per-output coalesced
__global__ __launch_bounds__(256) void k_inc1_bn(
    const float* __restrict__ q_ws, const float* __restrict__ inc1_w,
    const float* __restrict__ inc1_b,
    const float* __restrict__ bng, const float* __restrict__ bnb,
    const float* __restrict__ bnm, const float* __restrict__ bnv,
    float* __restrict__ y_ws)
{
  int b = blockIdx.x >> 5, og = blockIdx.x & 31;
  int wv = threadIdx.x >> 6, lane = threadIdx.x & 63;
  __shared__ float xs[CC];
  for (int t = threadIdx.x; t < CC; t += 256) xs[t] = q_ws[b*CC + t];
  __syncthreads();
  float x0 = xs[lane*6+0], x1 = xs[lane*6+1], x2 = xs[lane*6+2];
  float x3 = xs[lane*6+3], x4 = xs[lane*6+4], x5 = xs[lane*6+5];
#pragma unroll
  for (int u = 0; u < 8; u++) {
    int o = og*32 + wv*8 + u;
    const float* wr = inc1_w + (size_t)o * CC + lane*6;
    float2 wa = *(const float2*)wr;
    float2 wb = *(const float2*)(wr + 2);
    float2 wc = *(const float2*)(wr + 4);
    float p = wa.x*x0 + wa.y*x1 + wb.x*x2 + wb.y*x3 + wc.x*x4 + wc.y*x5;
    p = wave_sum(p);
    if (lane == 0) {
      float acc = p + inc1_b[o];
      float z = bng[o] * (acc - bnm[o]) * rsqrtf(bnv[o] + 1e-5f) + bnb[o];
      y_ws[b*1024 + o] = (z >= 0.f) ? z : 0.2f * z;
    }
  }
}

// ----------------------------------------- K5: inc2, wave-per-output coalesced
__global__ __launch_bounds__(256) void k_inc2(
    const float* __restrict__ y_ws, const float* __restrict__ inc2_w,
    const float* __restrict__ inc2_b, float* __restrict__ g2_ws)
{
  int b = blockIdx.x >> 5, og = blockIdx.x & 31;
  int wv = threadIdx.x >> 6, lane = threadIdx.x & 63;
  __shared__ __align__(16) float xs[1024];
  for (int t = threadIdx.x; t < 1024; t += 256) xs[t] = y_ws[b*1024 + t];
  __syncthreads();
  float4 X0 = *(const float4*)(xs + lane*16 + 0);
  float4 X1 = *(const float4*)(xs + lane*16 + 4);
  float4 X2 = *(const float4*)(xs + lane*16 + 8);
  float4 X3 = *(const float4*)(xs + lane*16 + 12);
#pragma unroll
  for (int u = 0; u < 8; u++) {
    int o = og*32 + wv*8 + u;
    const float* wr = inc2_w + (size_t)o * 1024 + lane*16;
    float4 W0 = *(const float4*)(wr + 0);
    float4 W1 = *(const float4*)(wr + 4);
    float4 W2 = *(const float4*)(wr + 8);
    float4 W3 = *(const float4*)(wr + 12);
    float p = W0.x*X0.x + W0.y*X0.y + W0.z*X0.z + W0.w*X0.w
            + W1.x*X1.x + W1.y*X1.y + W1.z*X1.z + W1.w*X1.w
            + W2.x*X2.x + W2.y*X2.y + W2.z*X2.z + W2.w*X2.w
            + W3.x*X3.x + W3.y*X3.y + W3.z*X3.z + W3.w*X3.w;
    p = wave_sum(p);
    if (lane == 0) g2_ws[b*1024 + o] = p + inc2_b[o];
  }
}

// --------------------------------------- K6: base partials over c-halves of red_w
__global__ __launch_bounds__(384) void k_base(
    const float* __restrict__ g2_ws, const float* __restrict__ q_ws,
    const float* __restrict__ red_w, float* __restrict__ basep)
{
  int b = blockIdx.x, h = blockIdx.y;
  int o = threadIdx.x;
  __shared__ __align__(16) float x[704];
  int c0 = h * 704;
  for (int t = threadIdx.x; t < 704; t += 384) {
    int c = c0 + t;
    x[t] = (c < 1024) ? g2_ws[b*1024 + c] : q_ws[b*CC + (c - 1024)];
  }
  __syncthreads();
  float acc = 0.f;
  for (int cc = 0; cc < 704; cc += 4) {
    float4 x4 = *(const float4*)(x + cc);
    acc += x4.x * red_w[(size_t)(c0 + cc    )*CC + o];
    acc += x4.y * red_w[(size_t)(c0 + cc + 1)*CC + o];
    acc += x4.z * red_w[(size_t)(c0 + cc + 2)*CC + o];
    acc += x4.w * red_w[(size_t)(c0 + cc + 3)*CC + o];
  }
  basep[(b*2 + h)*CC + o] = acc;
}

// --------------------------------------------- K7: out = base + coarse @ red_w3
__global__ __launch_bounds__(256) void k_out(
    const float* __restrict__ basep, const float* __restrict__ red_b,
    const float* __restrict__ red_w, const float* __restrict__ coarse,
    float* __restrict__ out)
{
  int gid = blockIdx.x * 256 + threadIdx.x;   // < 32*448*96 exactly
  int c4 = gid % 96;
  int row = gid / 96;                          // b*448 + m
  int b = row / 448;
  int c = c4 * 4;
  float4 p0 = *(const float4*)(basep + (b*2 + 0)*CC + c);
  float4 p1 = *(const float4*)(basep + (b*2 + 1)*CC + c);
  float4 rb = *(const float4*)(red_b + c);
  const float* cr = coarse + (size_t)row * 3;
  float cx = cr[0], cy = cr[1], cz = cr[2];
  float4 w0 = *(const float4*)(red_w + (size_t)1408*CC + c);
  float4 w1 = *(const float4*)(red_w + (size_t)1409*CC + c);
  float4 w2 = *(const float4*)(red_w + (size_t)1410*CC + c);
  float4 o4;
  o4.x = p0.x + p1.x + rb.x + cx*w0.x + cy*w1.x + cz*w2.x;
  o4.y = p0.y + p1.y + rb.y + cx*w0.y + cy*w1.y + cz*w2.y;
  o4.z = p0.z + p1.z + rb.z + cx*w0.z + cy*w1.z + cz*w2.z;
  o4.w = p0.w + p1.w + rb.w + cx*w0.w + cy*w1.w + cz*w2.w;
  *(float4*)(out + (size_t)row*CC + c) = o4;
}

extern "C" void kernel_launch(void* const* d_in, const int* in_sizes, int n_in,
                              void* d_out, int out_size, void* d_ws, size_t ws_size,
                              hipStream_t stream)
{
  (void)in_sizes; (void)n_in; (void)out_size; (void)ws_size;
  // d_in[0] is q (B,M,C): provably unused — attention softmax is uniform.
  const float* coarse = (const float*)d_in[1];
  const float* skel   = (const float*)d_in[2];
  const float* g1wr   = (const float*)d_in[3];
  const float* g1wl   = (const float*)d_in[4];
  const float* g1b    = (const float*)d_in[5];
  const float* g2wr   = (const float*)d_in[6];
  const float* g2wl   = (const float*)d_in[7];
  const float* g2b    = (const float*)d_in[8];
  const float* projw  = (const float*)d_in[9];
  const float* projb  = (const float*)d_in[10];
  const float* aiw    = (const float*)d_in[11];
  const float* aib    = (const float*)d_in[12];
  const float* aow    = (const float*)d_in[13];
  const float* aob    = (const float*)d_in[14];
  const float* i1w    = (const float*)d_in[15];
  const float* i1b    = (const float*)d_in[16];
  const float* bng    = (const float*)d_in[17];
  const float* bnb    = (const float*)d_in[18];
  const float* bnm    = (const float*)d_in[19];
  const float* bnv    = (const float*)d_in[20];
  const float* i2w    = (const float*)d_in[21];
  const float* i2b    = (const float*)d_in[22];
  const float* redw   = (const float*)d_in[23];
  const float* redb   = (const float*)d_in[24];
  float* out = (float*)d_out;

  char* ws = (char*)d_ws;
  int*   idx_ws = (int*)(ws + WS_IDX);
  float* h1_ws  = (float*)(ws + WS_H1);
  float* pmax   = (float*)(ws + WS_PMAX);
  float* q_ws   = (float*)(ws + WS_Q);
  float* y_ws   = (float*)(ws + WS_Y);
  float* g2_ws  = (float*)(ws + WS_G2);
  float* basep  = (float*)(ws + WS_BASEP);
  float* kv_ws  = (float*)(ws + WS_KV);   // reuses idx region (dead after K2)
  float* vv_ws  = (float*)(ws + WS_VV);

  k_knn_gc1<<<4096, 256, 0, stream>>>(skel, g1wr, g1wl, g1b, idx_ws, h1_ws);
  k_gc2_max<<<dim3(32, 16), 256, 0, stream>>>(h1_ws, idx_ws, g2wr, g2wl, g2b, pmax);
  k_proxy_kv<<<32, 384, 0, stream>>>(pmax, projw, projb, kv_ws);
  k_mv384<<<dim3(32, 12), 256, 0, stream>>>(kv_ws, aiw, 2*CC, aib, 2*CC, vv_ws); // vv
  k_mv384<<<dim3(32, 12), 256, 0, stream>>>(vv_ws, aow, 0,    aob, 0,    q_ws);  // q
  k_inc1_bn<<<1024, 256, 0, stream>>>(q_ws, i1w, i1b, bng, bnb, bnm, bnv, y_ws);
  k_inc2<<<1024, 256, 0, stream>>>(y_ws, i2w, i2b, g2_ws);
  k_base<<<dim3(32, 2), 384, 0, stream>>>(g2_ws, q_ws, redw, basep);
  k_out<<<5376, 256, 0, stream>>>(basep, redb, redw, coarse, out);
}

// Round 3
// 256.585 us; speedup vs baseline: 1.8488x; 1.2144x over previous
//
#include <hip/hip_runtime.h>

#define NB 32      // batches
#define MM 448
#define CC 384
#define SS 512
#define KNN 8

// workspace byte offsets
#define WS_IDX   0u
#define WS_H1    524288u                 // int idx[32][512][8] before this
#define WS_PMAX  (WS_H1 + 4194304u)      // float h1[32][512][64]
#define WS_Q     (WS_PMAX + 262144u)     // float pmax[32][8][128] (half used)
#define WS_Y     (WS_Q + 49152u)         // float y[32][1024]
#define WS_G2    (WS_Y + 131072u)        // float g2[32][1024]
#define WS_BASEP (WS_G2 + 131072u)       // float basep[32][384]
// kv/vv reuse the idx region (idx dead after K2); pp reuses h1 region (dead after K2)
#define WS_KV    WS_IDX
#define WS_VV    (WS_IDX + 49152u)
#define WS_PP    WS_H1                   // float pp[44][32][384] = 2.16 MB < 4 MB

__device__ __forceinline__ float wave_sum(float v) {
#pragma unroll
  for (int m = 1; m < 64; m <<= 1) v += __shfl_xor(v, m, 64);
  return v;
}

// ------------------------------------------------- K1: KNN + gc1, wave-per-point
__global__ __launch_bounds__(256) void k_knn_gc1(
    const float* __restrict__ skel,
    const float* __restrict__ w1root, const float* __restrict__ w1rel,
    const float* __restrict__ b1,
    int* __restrict__ idx_ws, float* __restrict__ h1_ws)
{
  int b   = blockIdx.x >> 7;          // 128 groups of 4 points per batch
  int grp = blockIdx.x & 127;
  __shared__ __align__(16) float4 sk[SS];
  const float* sb = skel + b * SS * 3;
  for (int t = threadIdx.x; t < SS; t += 256)
    sk[t] = make_float4(sb[t*3+0], sb[t*3+1], sb[t*3+2], 0.f);
  __syncthreads();

  int wave = threadIdx.x >> 6, lane = threadIdx.x & 63;
  int i = grp * 4 + wave;             // this wave's point
  float4 pi = sk[i];

  // lane owns candidates j = lane + 64*t
  float bd[KNN];
#pragma unroll
  for (int t = 0; t < KNN; t++) {
    int j = lane + (t << 6);
    float4 p = sk[j];
    float d2;
    {
      // match reference arithmetic exactly: (dx^2+dy^2)+dz^2, no fma contraction
#pragma clang fp contract(off)
      float dx = pi.x - p.x, dy = pi.y - p.y, dz = pi.z - p.z;
      d2 = (dx*dx + dy*dy) + dz*dz;
    }
    bd[t] = (j == i) ? 3e38f : d2;
  }

  // 8 rounds: global argmin (tie -> lower j, matching lax.top_k stability)
  int win[KNN];
  int* idx_base = idx_ws + (size_t)(b*SS + i) * KNN;
#pragma unroll
  for (int t = 0; t < KNN; t++) {
    float bestd = bd[0]; int bests = 0;
#pragma unroll
    for (int s = 1; s < KNN; s++)
      if (bd[s] < bestd) { bestd = bd[s]; bests = s; }
    int bestj = lane + (bests << 6);
#pragma unroll
    for (int m = 1; m < 64; m <<= 1) {
      float od = __shfl_xor(bestd, m, 64);
      int   oj = __shfl_xor(bestj, m, 64);
      if (od < bestd || (od == bestd && oj < bestj)) { bestd = od; bestj = oj; }
    }
    win[t] = bestj;                               // uniform across wave
    if (lane == t) idx_base[t] = bestj;
    if ((bestj & 63) == lane) {
      int sl = bestj >> 6;
#pragma unroll
      for (int s = 0; s < KNN; s++) if (s == sl) bd[s] = 3e38f;
    }
  }

  // neighbor coordinate sum in k-order (matches reference sum order)
  float a0 = 0.f, a1 = 0.f, a2 = 0.f;
#pragma unroll
  for (int t = 0; t < KNN; t++) {
    float4 n = sk[win[t]];
    a0 += n.x; a1 += n.y; a2 += n.z;
  }

  // gc1: 64 channels = 64 lanes, coalesced
  int c = lane;
  float h = b1[c] + pi.x*w1root[c] + pi.y*w1root[64+c] + pi.z*w1root[128+c]
                  + a0*w1rel[c]   + a1*w1rel[64+c]   + a2*w1rel[128+c];
  h = fmaxf(h, 0.f);
  h1_ws[(size_t)(b*SS + i) * 64 + lane] = h;
}

// ---------------- K2: gc2 + chunk max, LDS-staged weights, 64 rows/block
// thread: rg = t>>3 -> rows {2rg, 2rg+1}; og = t&7 -> cols og*16..+16
// W staged per k-half in og-plane swizzle: plane stride 516 -> conflict-free reads
__global__ __launch_bounds__(256) void k_gc2_max(
    const float* __restrict__ h1_ws, const int* __restrict__ idx_ws,
    const float* __restrict__ w2root, const float* __restrict__ w2rel,
    const float* __restrict__ b2, float* __restrict__ pmax)
{
  int b = blockIdx.x, chunk = blockIdx.y;
  int i0 = chunk * 64;
  __shared__ __align__(16) float smem[12992];
  float* wroot_s = smem;                 // 8 planes * 516 = 4128
  float* wrel_s  = smem + 4128;          // 4128
  float* hr_s    = smem + 8256;          // 64*33 = 2112
  float* ag_s    = smem + 10368;         // 2112
  int*   nbs     = (int*)(smem + 12480); // 512 ints

  const float* h1b = h1_ws + (size_t)b * SS * 64;

  nbs[threadIdx.x]       = idx_ws[(b*SS + i0)*KNN + threadIdx.x];
  nbs[threadIdx.x + 256] = idx_ws[(b*SS + i0)*KNN + threadIdx.x + 256];

  int rg = threadIdx.x >> 3, og = threadIdx.x & 7;
  int r0 = rg*2, r1 = rg*2 + 1;
  float acc0[16], acc1[16];
#pragma unroll
  for (int u = 0; u < 16; u++) { acc0[u] = 0.f; acc1[u] = 0.f; }

  for (int p = 0; p < 2; p++) {
    __syncthreads();   // protect LDS (covers nbs on p=0, prior k-loop on p=1)
    // stage W k-half: 32 k-rows x 128 cols each matrix, og-plane swizzled
#pragma unroll
    for (int p2 = 0; p2 < 16; p2++) {
      int idx = threadIdx.x + 256*p2;
      int kk = idx >> 7, c = idx & 127;
      int ogs = c >> 4, j = c & 15;
      int dst = ogs*516 + kk*16 + j;
      int srco = (p*32 + kk)*128 + c;
      wroot_s[dst] = w2root[srco];
      wrel_s[dst]  = w2rel[srco];
    }
    // stage hr slice + neighbor-agg slice: 64 rows x 32 kk
#pragma unroll
    for (int p2 = 0; p2 < 8; p2++) {
      int idx = threadIdx.x + 256*p2;
      int r = idx >> 5, kk = idx & 31;
      hr_s[r*33 + kk] = h1b[(i0 + r)*64 + p*32 + kk];
      float s = 0.f;
#pragma unroll
      for (int k = 0; k < KNN; k++)
        s += h1b[nbs[r*8 + k]*64 + p*32 + kk];
      ag_s[r*33 + kk] = s;
    }
    __syncthreads();
    const float* wr = wroot_s + og*516;
    const float* wl = wrel_s  + og*516;
#pragma unroll 2
    for (int kk = 0; kk < 32; kk++) {
      float h0 = hr_s[r0*33 + kk], h1v = hr_s[r1*33 + kk];
      float a0 = ag_s[r0*33 + kk], a1v = ag_s[r1*33 + kk];
      float4 R0 = *(const float4*)(wr + kk*16);
      float4 R1 = *(const float4*)(wr + kk*16 + 4);
      float4 R2 = *(const float4*)(wr + kk*16 + 8);
      float4 R3 = *(const float4*)(wr + kk*16 + 12);
      float4 L0 = *(const float4*)(wl + kk*16);
      float4 L1 = *(const float4*)(wl + kk*16 + 4);
      float4 L2 = *(const float4*)(wl + kk*16 + 8);
      float4 L3 = *(const float4*)(wl + kk*16 + 12);
      acc0[0]+=h0*R0.x+a0*L0.x;  acc1[0]+=h1v*R0.x+a1v*L0.x;
      acc0[1]+=h0*R0.y+a0*L0.y;  acc1[1]+=h1v*R0.y+a1v*L0.y;
      acc0[2]+=h0*R0.z+a0*L0.z;  acc1[2]+=h1v*R0.z+a1v*L0.z;
      acc0[3]+=h0*R0.w+a0*L0.w;  acc1[3]+=h1v*R0.w+a1v*L0.w;
      acc0[4]+=h0*R1.x+a0*L1.x;  acc1[4]+=h1v*R1.x+a1v*L1.x;
      acc0[5]+=h0*R1.y+a0*L1.y;  acc1[5]+=h1v*R1.y+a1v*L1.y;
      acc0[6]+=h0*R1.z+a0*L1.z;  acc1[6]+=h1v*R1.z+a1v*L1.z;
      acc0[7]+=h0*R1.w+a0*L1.w;  acc1[7]+=h1v*R1.w+a1v*L1.w;
      acc0[8]+=h0*R2.x+a0*L2.x;  acc1[8]+=h1v*R2.x+a1v*L2.x;
      acc0[9]+=h0*R2.y+a0*L2.y;  acc1[9]+=h1v*R2.y+a1v*L2.y;
      acc0[10]+=h0*R2.z+a0*L2.z; acc1[10]+=h1v*R2.z+a1v*L2.z;
      acc0[11]+=h0*R2.w+a0*L2.w; acc1[11]+=h1v*R2.w+a1v*L2.w;
      acc0[12]+=h0*R3.x+a0*L3.x; acc1[12]+=h1v*R3.x+a1v*L3.x;
      acc0[13]+=h0*R3.y+a0*L3.y; acc1[13]+=h1v*R3.y+a1v*L3.y;
      acc0[14]+=h0*R3.z+a0*L3.z; acc1[14]+=h1v*R3.z+a1v*L3.z;
      acc0[15]+=h0*R3.w+a0*L3.w; acc1[15]+=h1v*R3.w+a1v*L3.w;
    }
  }
  __syncthreads();
  // per-thread row-pair max -> m[32][128] (reuse smem), then column max over rg
  float* m = smem;
#pragma unroll
  for (int u = 0; u < 16; u++)
    m[rg*128 + og*16 + u] = fmaxf(acc0[u], acc1[u]);
  __syncthreads();
  if (threadIdx.x < 128) {
    int col = threadIdx.x;
    float mx = -3e38f;
#pragma unroll 8
    for (int g = 0; g < 32; g++) mx = fmaxf(mx, m[g*128 + col]);
    pmax[(b*8 + chunk)*128 + col] = mx + b2[col];   // bias commutes with max
  }
}

// ------------------------------------------------- K3a: proxy max + kv (coalesced)
__global__ __launch_bounds__(384) void k_proxy_kv(
    const float* __restrict__ pmax,
    const float* __restrict__ proj_w, const float* __restrict__ proj_b,
    float* __restrict__ kv_ws)
{
  int b = blockIdx.x, t = threadIdx.x;
  __shared__ float proxy[128];
  if (t < 128) {
    float m = -3e38f;
    for (int ch = 0; ch < 8; ch++) m = fmaxf(m, pmax[(b*8 + ch)*128 + t]);
    proxy[t] = m;
  }
  __syncthreads();
  float acc = proj_b[t];
  for (int s = 0; s < 128; s++) acc += proxy[s] * proj_w[s*CC + t];   // coalesced
  kv_ws[b*CC + t] = acc;
}

// ------------------------- K3b/K3c: generic 384->384 matvec, wave-per-output dot
__global__ __launch_bounds__(256) void k_mv384(
    const float* __restrict__ xin, const float* __restrict__ w, int row0,
    const float* __restrict__ bias, int bias0, float* __restrict__ out)
{
  int b = blockIdx.x, og = blockIdx.y;
  int wv = threadIdx.x >> 6, lane = threadIdx.x & 63;
  __shared__ float xs[CC];
  for (int t = threadIdx.x; t < CC; t += 256) xs[t] = xin[b*CC + t];
  __syncthreads();
  float x0 = xs[lane*6+0], x1 = xs[lane*6+1], x2 = xs[lane*6+2];
  float x3 = xs[lane*6+3], x4 = xs[lane*6+4], x5 = xs[lane*6+5];
#pragma unroll
  for (int u = 0; u < 8; u++) {
    int o = og*32 + wv*8 + u;
    const float* wr = w + (size_t)(row0 + o) * CC + lane*6;
    float2 wa = *(const float2*)wr;
    float2 wb = *(const float2*)(wr + 2);
    float2 wc = *(const float2*)(wr + 4);
    float p = wa.x*x0 + wa.y*x1 + wb.x*x2 + wb.y*x3 + wc.x*x4 + wc.y*x5;
    p = wave_sum(p);
    if (lane == 0) out[b*CC + o] = bias[bias0 + o] + p;
  }
}

// ------------------------------- K4: inc1 + BN + leaky, wave-per-output coalesced
__global__ __launch_bounds__(256) void k_inc1_bn(
    const float* __restrict__ q_ws, const float* __restrict__ inc1_w,
    const float* __restrict__ inc1_b,
    const float* __restrict__ bng, const float* __restrict__ bnb,
    const float* __restrict__ bnm, const float* __restrict__ bnv,
    float* __restrict__ y_ws)
{
  int b = blockIdx.x >> 5, og = blockIdx.x & 31;
  int wv = threadIdx.x >> 6, lane = threadIdx.x & 63;
  __shared__ float xs[CC];
  for (int t = threadIdx.x; t < CC; t += 256) xs[t] = q_ws[b*CC + t];
  __syncthreads();
  float x0 = xs[lane*6+0], x1 = xs[lane*6+1], x2 = xs[lane*6+2];
  float x3 = xs[lane*6+3], x4 = xs[lane*6+4], x5 = xs[lane*6+5];
#pragma unroll
  for (int u = 0; u < 8; u++) {
    int o = og*32 + wv*8 + u;
    const float* wr = inc1_w + (size_t)o * CC + lane*6;
    float2 wa = *(const float2*)wr;
    float2 wb = *(const float2*)(wr + 2);
    float2 wc = *(const float2*)(wr + 4);
    float p = wa.x*x0 + wa.y*x1 + wb.x*x2 + wb.y*x3 + wc.x*x4 + wc.y*x5;
    p = wave_sum(p);
    if (lane == 0) {
      float acc = p + inc1_b[o];
      float z = bng[o] * (acc - bnm[o]) * rsqrtf(bnv[o] + 1e-5f) + bnb[o];
      y_ws[b*1024 + o] = (z >= 0.f) ? z : 0.2f * z;
    }
  }
}

// ----------------------------------------- K5: inc2, wave-per-output coalesced
__global__ __launch_bounds__(256) void k_inc2(
    const float* __restrict__ y_ws, const float* __restrict__ inc2_w,
    const float* __restrict__ inc2_b, float* __restrict__ g2_ws)
{
  int b = blockIdx.x >> 5, og = blockIdx.x & 31;
  int wv = threadIdx.x >> 6, lane = threadIdx.x & 63;
  __shared__ __align__(16) float xs[1024];
  for (int t = threadIdx.x; t < 1024; t += 256) xs[t] = y_ws[b*1024 + t];
  __syncthreads();
  float4 X0 = *(const float4*)(xs + lane*16 + 0);
  float4 X1 = *(const float4*)(xs + lane*16 + 4);
  float4 X2 = *(const float4*)(xs + lane*16 + 8);
  float4 X3 = *(const float4*)(xs + lane*16 + 12);
#pragma unroll
  for (int u = 0; u < 8; u++) {
    int o = og*32 + wv*8 + u;
    const float* wr = inc2_w + (size_t)o * 1024 + lane*16;
    float4 W0 = *(const float4*)(wr + 0);
    float4 W1 = *(const float4*)(wr + 4);
    float4 W2 = *(const float4*)(wr + 8);
    float4 W3 = *(const float4*)(wr + 12);
    float p = W0.x*X0.x + W0.y*X0.y + W0.z*X0.z + W0.w*X0.w
            + W1.x*X1.x + W1.y*X1.y + W1.z*X1.z + W1.w*X1.w
            + W2.x*X2.x + W2.y*X2.y + W2.z*X2.z + W2.w*X2.w
            + W3.x*X3.x + W3.y*X3.y + W3.z*X3.z + W3.w*X3.w;
    p = wave_sum(p);
    if (lane == 0) g2_ws[b*1024 + o] = p + inc2_b[o];
  }
}

// ------------- K6a: base partial GEMM: pp[cg][b][o] = x[b][c0:c0+32] @ W[c0:c0+32]
// grid (44 c-chunks, 6 col-chunks of 64); W read exactly once across the grid
__global__ __launch_bounds__(256) void k_basep(
    const float* __restrict__ g2_ws, const float* __restrict__ q_ws,
    const float* __restrict__ red_w, float* __restrict__ pp)
{
  int cg = blockIdx.x;          // 0..43 (c0 = cg*32; <1024 -> g2, else q)
  int o0 = blockIdx.y * 64;     // 0..5
  int c0 = cg * 32;
  __shared__ __align__(16) float xs[32*33];   // [c][b] padded
  __shared__ __align__(16) float wt[32*64];   // [c][o]
#pragma unroll
  for (int p = 0; p < 8; p++) {
    int idx = threadIdx.x + 256*p;
    int c = idx >> 6, o = idx & 63;
    wt[idx] = red_w[(size_t)(c0 + c)*CC + o0 + o];   // wave = 256B contiguous
  }
  {
    int b = threadIdx.x >> 3, cp = threadIdx.x & 7;
    const float* src = (cg < 32) ? (g2_ws + b*1024 + c0)
                                 : (q_ws  + b*CC   + (c0 - 1024));
    float4 v = *(const float4*)(src + cp*4);
    xs[(cp*4+0)*33 + b] = v.x;
    xs[(cp*4+1)*33 + b] = v.y;
    xs[(cp*4+2)*33 + b] = v.z;
    xs[(cp*4+3)*33 + b] = v.w;
  }
  __syncthreads();
  int b = threadIdx.x >> 3, og = threadIdx.x & 7;
  float acc[8];
#pragma unroll
  for (int u = 0; u < 8; u++) acc[u] = 0.f;
#pragma unroll 8
  for (int c = 0; c < 32; c++) {
    float xv = xs[c*33 + b];
    float4 w0 = *(const float4*)(wt + c*64 + og*8);
    float4 w1 = *(const float4*)(wt + c*64 + og*8 + 4);
    acc[0] += xv*w0.x; acc[1] += xv*w0.y; acc[2] += xv*w0.z; acc[3] += xv*w0.w;
    acc[4] += xv*w1.x; acc[5] += xv*w1.y; acc[6] += xv*w1.z; acc[7] += xv*w1.w;
  }
  float* dst = pp + (size_t)(cg*32 + b)*CC + o0 + og*8;
  *(float4*)dst       = make_float4(acc[0], acc[1], acc[2], acc[3]);
  *(float4*)(dst + 4) = make_float4(acc[4], acc[5], acc[6], acc[7]);
}

// ------------------------------------ K6b: reduce 44 partials -> basep[32][384]
__global__ __launch_bounds__(256) void k_base_red(
    const float* __restrict__ pp, float* __restrict__ basep)
{
  int idx = blockIdx.x * 256 + threadIdx.x;   // < 12288
  float s = 0.f;
#pragma unroll 4
  for (int cg = 0; cg < 44; cg++) s += pp[cg*12288 + idx];
  basep[idx] = s;
}

// --------------------------------------------- K7: out = base + coarse @ red_w3
__global__ __launch_bounds__(256) void k_out(
    const float* __restrict__ basep, const float* __restrict__ red_b,
    const float* __restrict__ red_w, const float* __restrict__ coarse,
    float* __restrict__ out)
{
  int gid = blockIdx.x * 256 + threadIdx.x;   // < 32*448*96 exactly
  int c4 = gid % 96;
  int row = gid / 96;                          // b*448 + m
  int b = row / 448;
  int c = c4 * 4;
  float4 p0 = *(const float4*)(basep + b*CC + c);
  float4 rb = *(const float4*)(red_b + c);
  const float* cr = coarse + (size_t)row * 3;
  float cx = cr[0], cy = cr[1], cz = cr[2];
  float4 w0 = *(const float4*)(red_w + (size_t)1408*CC + c);
  float4 w1 = *(const float4*)(red_w + (size_t)1409*CC + c);
  float4 w2 = *(const float4*)(red_w + (size_t)1410*CC + c);
  float4 o4;
  o4.x = p0.x + rb.x + cx*w0.x + cy*w1.x + cz*w2.x;
  o4.y = p0.y + rb.y + cx*w0.y + cy*w1.y + cz*w2.y;
  o4.z = p0.z + rb.z + cx*w0.z + cy*w1.z + cz*w2.z;
  o4.w = p0.w + rb.w + cx*w0.w + cy*w1.w + cz*w2.w;
  *(float4*)(out + (size_t)row*CC + c) = o4;
}

extern "C" void kernel_launch(void* const* d_in, const int* in_sizes, int n_in,
                              void* d_out, int out_size, void* d_ws, size_t ws_size,
                              hipStream_t stream)
{
  (void)in_sizes; (void)n_in; (void)out_size; (void)ws_size;
  // d_in[0] is q (B,M,C): provably unused — attention softmax is uniform.
  const float* coarse = (const float*)d_in[1];
  const float* skel   = (const float*)d_in[2];
  const float* g1wr   = (const float*)d_in[3];
  const float* g1wl   = (const float*)d_in[4];
  const float* g1b    = (const float*)d_in[5];
  const float* g2wr   = (const float*)d_in[6];
  const float* g2wl   = (const float*)d_in[7];
  const float* g2b    = (const float*)d_in[8];
  const float* projw  = (const float*)d_in[9];
  const float* projb  = (const float*)d_in[10];
  const float* aiw    = (const float*)d_in[11];
  const float* aib    = (const float*)d_in[12];
  const float* aow    = (const float*)d_in[13];
  const float* aob    = (const float*)d_in[14];
  const float* i1w    = (const float*)d_in[15];
  const float* i1b    = (const float*)d_in[16];
  const float* bng    = (const float*)d_in[17];
  const float* bnb    = (const float*)d_in[18];
  const float* bnm    = (const float*)d_in[19];
  const float* bnv    = (const float*)d_in[20];
  const float* i2w    = (const float*)d_in[21];
  const float* i2b    = (const float*)d_in[22];
  const float* redw   = (const float*)d_in[23];
  const float* redb   = (const float*)d_in[24];
  float* out = (float*)d_out;

  char* ws = (char*)d_ws;
  int*   idx_ws = (int*)(ws + WS_IDX);
  float* h1_ws  = (float*)(ws + WS_H1);
  float* pmax   = (float*)(ws + WS_PMAX);
  float* q_ws   = (float*)(ws + WS_Q);
  float* y_ws   = (float*)(ws + WS_Y);
  float* g2_ws  = (float*)(ws + WS_G2);
  float* basep  = (float*)(ws + WS_BASEP);
  float* kv_ws  = (float*)(ws + WS_KV);   // reuses idx region (dead after K2)
  float* vv_ws  = (float*)(ws + WS_VV);
  float* pp     = (float*)(ws + WS_PP);   // reuses h1 region (dead after K2)

  k_knn_gc1<<<4096, 256, 0, stream>>>(skel, g1wr, g1wl, g1b, idx_ws, h1_ws);
  k_gc2_max<<<dim3(32, 8), 256, 0, stream>>>(h1_ws, idx_ws, g2wr, g2wl, g2b, pmax);
  k_proxy_kv<<<32, 384, 0, stream>>>(pmax, projw, projb, kv_ws);
  k_mv384<<<dim3(32, 12), 256, 0, stream>>>(kv_ws, aiw, 2*CC, aib, 2*CC, vv_ws); // vv
  k_mv384<<<dim3(32, 12), 256, 0, stream>>>(vv_ws, aow, 0,    aob, 0,    q_ws);  // q
  k_inc1_bn<<<1024, 256, 0, stream>>>(q_ws, i1w, i1b, bng, bnb, bnm, bnv, y_ws);
  k_inc2<<<1024, 256, 0, stream>>>(y_ws, i2w, i2b, g2_ws);
  k_basep<<<dim3(44, 6), 256, 0, stream>>>(g2_ws, q_ws, redw, pp);
  k_base_red<<<48, 256, 0, stream>>>(pp, basep);
  k_out<<<5376, 256, 0, stream>>>(basep, redb, redw, coarse, out);
}